// Round 13
// baseline (838.953 us; speedup 1.0000x reference)
//
#include <hip/hip_runtime.h>
#include <hip/hip_bf16.h>
#include <stdint.h>
#include <stddef.h>

static constexpr int BB = 16, NN = 256, TT = 4, HH = 128;
static constexpr int MM = BB * NN;     // 4096 rows
static constexpr int CC = 512;         // 4*H gate width
static constexpr int OUTV = 1000;
static constexpr int MAXS = 15;
static constexpr int SP = 132;         // f32 state row pitch in LDS

typedef float f32x4 __attribute__((ext_vector_type(4)));
typedef short s16x8 __attribute__((ext_vector_type(8)));

__device__ __forceinline__ float sigf(float x) { return 1.0f / (1.0f + __expf(-x)); }
__device__ __forceinline__ float tanhr(float x) { return 2.0f / (1.0f + __expf(-2.0f * x)) - 1.0f; }
__device__ __forceinline__ unsigned short f2bu(float a) {
  return __builtin_bit_cast(unsigned short, __float2bfloat16(a));
}
__device__ __forceinline__ unsigned int packh(float a, float b) {
  return (unsigned int)f2bu(a) | ((unsigned int)f2bu(b) << 16);
}
__device__ __forceinline__ float blo(unsigned int u) { return __builtin_bit_cast(float, u << 16); }
__device__ __forceinline__ float bhi(unsigned int u) { return __builtin_bit_cast(float, u & 0xffff0000u); }

// ---------------- single setup dispatch ----------------
// blocks 0..15: per-batch CSR (block-local LDS)
// blocks 16..399: weight swizzle -> bf16 B-fragment order (384 x 512 = 196608 elems)
// blocks 400..524: XW0 vocab table tab[v] = embed[v]@Wi0 + b0 (125 x 8 rows)
__global__ __launch_bounds__(512) void setup_kernel(
    const int* __restrict__ tb, const int* __restrict__ fb,
    int* __restrict__ offs, int* __restrict__ edges,
    const float* __restrict__ Wh0, const float* __restrict__ Wi1, const float* __restrict__ Wh1,
    const float* __restrict__ embed, const float* __restrict__ Wi0, const float* __restrict__ b0,
    unsigned short* __restrict__ swz, float* __restrict__ tab) {
  const int blk = blockIdx.x;
  const int tid = threadIdx.x;
  __shared__ int cnt[256], sc[256], cur[256];
  __shared__ float A[8][HH];

  if (blk < 16) {
    if (tid < 256) cnt[tid] = 0;
    __syncthreads();
    const int n = tid >> 1, bit = tid & 1;
    const int tgt = bit ? fb[blk * NN + n] : tb[blk * NN + n];
    atomicAdd(&cnt[tgt], 1);
    __syncthreads();
    if (tid < 256) sc[tid] = cnt[tid];
    __syncthreads();
    for (int ofs = 1; ofs < 256; ofs <<= 1) {
      int t2 = (tid < 256 && tid >= ofs) ? sc[tid - ofs] : 0;
      __syncthreads();
      if (tid < 256) sc[tid] += t2;
      __syncthreads();
    }
    if (tid < 256) { offs[blk * NN + tid] = blk * 2 * NN + sc[tid] - cnt[tid]; cur[tid] = 0; }
    if (blk == 0 && tid == 0) offs[MM] = 2 * MM;
    __syncthreads();
    int lpos = sc[tgt] - cnt[tgt] + atomicAdd(&cur[tgt], 1);
    edges[blk * 2 * NN + lpos] = (n << 1) | bit;
    return;
  }
  if (blk < 400) {
    int i = (blk - 16) * 512 + tid;  // 0..196607
    int mtx = i >> 16, ii = i & 65535;
    const float* W = (mtx == 0) ? Wh0 : (mtx == 1) ? Wi1 : Wh1;
    int j = ii & 7, ln = (ii >> 3) & 63, kb = (ii >> 9) & 3, ct = ii >> 11;
    int n = ln & 15, q = ln >> 4;
    swz[i] = f2bu(W[(kb * 32 + q * 8 + j) * CC + ct * 16 + n]);
    return;
  }
  // XW0 table: 8 rows/block, thread j = one of 512 gate-cols
  const int v0 = (blk - 400) * 8;
  for (int s = tid; s < 8 * HH; s += 512) {
    int r = s >> 7, k = s & 127;
    A[r][k] = embed[(size_t)(v0 + r) * HH + k];
  }
  __syncthreads();
  const int j = tid;
  float za[8];
  {
    float ba = b0[j];
#pragma unroll
    for (int r = 0; r < 8; ++r) za[r] = ba;
  }
#pragma unroll 4
  for (int k = 0; k < HH; ++k) {
    float wv = Wi0[k * CC + j];
#pragma unroll
    for (int r = 0; r < 8; ++r) za[r] += A[r][k] * wv;
  }
#pragma unroll
  for (int r = 0; r < 8; ++r) tab[(size_t)(v0 + r) * CC + j] = za[r];
}

// ---------------- fused per-step kernel ----------------
// 16 rows/block, 512 threads = 8 waves; XCD-pinned batches (blockIdx === b mod 8).
// agg prologue + 4 tokens x 2 layers LSTM (MFMA, gates in D regs) + branch softmax
// + bf16-packed writeout. Death step (s == steps[b]): only the exit-owner block runs,
// aggregates, and computes the final 512->1000 logits in-place (no separate kernel).
// tab D-init is pipelined one token ahead (prefetch during layer-1).

__global__ __launch_bounds__(512) void step_kernel(
    const unsigned int* __restrict__ Pr, unsigned int* __restrict__ Pw,
    const float* __restrict__ wtR, const float* __restrict__ wfR,
    float* __restrict__ wtW, float* __restrict__ wfW,
    const int* __restrict__ offs, const int* __restrict__ edges,
    const float* __restrict__ tab,
    const unsigned short* __restrict__ swzWh0, const unsigned short* __restrict__ swzWi1,
    const unsigned short* __restrict__ swzWh1, const float* __restrict__ b1,
    const float* __restrict__ Wb, const float* __restrict__ bb,
    const float* __restrict__ Wo, const float* __restrict__ bo, float* __restrict__ out,
    const int* __restrict__ data, const int* __restrict__ exi,
    const int* __restrict__ steps, int step) {
  const int B = blockIdx.x;
  const int b = (B & 7) | (((B >> 3) & 1) << 3);  // batch, pinned to XCD b%8
  const int g16 = B >> 4;                          // node-group 0..15 within batch
  const int row0 = b * NN + g16 * 16;
  const int sb = steps[b];
  const bool aggLive = (step >= 1) && ((step - 1) < sb);
  const bool lstmLive = (step < sb);
  if (!aggLive && !lstmLive) return;

  const int exnode = exi[b];
  const int exm = exnode - (g16 * 16);
  const bool ownExit = (exm >= 0 && exm < 16);
  if (!lstmLive && !ownExit) return;  // dead batch, non-exit block: nothing to do

  const int tid = threadIdx.x;
  const int w = tid >> 6;
  const int lane = tid & 63;
  const int n16 = lane & 15, qq = lane >> 4;
  const int kcol = w * 16 + n16;
  const int basePos = ((kcol >> 5) * 64 + ((kcol >> 3) & 3) * 16) * 8 + (kcol & 7);

  __shared__ float c0L[16 * SP], h0L[16 * SP], c1L[16 * SP], h1L[16 * SP];
  __shared__ __align__(16) unsigned short hA0[2][2048], hA1[2][2048];  // double-buffered
  __shared__ float exitP[512];
  __shared__ float ipL[16];
  __shared__ int toks[64];

  // ----- HOISTED persistent loads: in flight during the gather
  s16x8 B0f[4][4], B1f[4][4];
  float b1v[4];
  const s16x8* pWh0 = (const s16x8*)swzWh0;
  const s16x8* pWh1 = (const s16x8*)swzWh1;
  const s16x8* pWi1 = (const s16x8*)swzWi1;
  if (lstmLive) {
#pragma unroll
    for (int g = 0; g < 4; ++g) {
      int ci = w + 8 * g;
#pragma unroll
      for (int kb = 0; kb < 4; ++kb) {
        B0f[g][kb] = pWh0[(ci * 4 + kb) * 64 + lane];
        B1f[g][kb] = pWh1[(ci * 4 + kb) * 64 + lane];
      }
      b1v[g] = b1[ci * 16 + n16];
    }
    if (tid < 64) toks[tid] = data[(row0 + (tid >> 2)) * TT + (tid & 3)];
  }

  // ----- prologue: aggregate previous step (16 nodes, 32 lanes each)
  if (aggLive) {
    const int l = tid & 31;
    const int m = tid >> 5;
    const int node = row0 + m;
    const int beg = offs[node], end = offs[node + 1];
    float ac0[4] = {0,0,0,0}, ah0[4] = {0,0,0,0}, ac1[4] = {0,0,0,0}, ah1[4] = {0,0,0,0};
    float wsum = 0.f;
    for (int e = beg; e < end; ++e) {
      int rec = edges[e];
      int src = (b << 8) + (rec >> 1);
      float wv = (rec & 1) ? wfR[src] : wtR[src];
      wsum += wv;
      const uint4* pr = (const uint4*)(Pr + (size_t)src * 256 + 8 * l);
      uint4 u0 = pr[0], u1 = pr[1];
      ac0[0] += wv * blo(u0.x); ac0[1] += wv * bhi(u0.x);
      ac0[2] += wv * blo(u0.y); ac0[3] += wv * bhi(u0.y);
      ah0[0] += wv * blo(u0.z); ah0[1] += wv * bhi(u0.z);
      ah0[2] += wv * blo(u0.w); ah0[3] += wv * bhi(u0.w);
      ac1[0] += wv * blo(u1.x); ac1[1] += wv * bhi(u1.x);
      ac1[2] += wv * blo(u1.y); ac1[3] += wv * bhi(u1.y);
      ah1[0] += wv * blo(u1.z); ah1[1] += wv * bhi(u1.z);
      ah1[2] += wv * blo(u1.w); ah1[3] += wv * bhi(u1.w);
    }
    float inv = 1.0f / (wsum + 1e-7f);
    float4 o0 = { ac0[0]*inv, ac0[1]*inv, ac0[2]*inv, ac0[3]*inv };
    float4 o1 = { ah0[0]*inv, ah0[1]*inv, ah0[2]*inv, ah0[3]*inv };
    float4 o2 = { ac1[0]*inv, ac1[1]*inv, ac1[2]*inv, ac1[3]*inv };
    float4 o3 = { ah1[0]*inv, ah1[1]*inv, ah1[2]*inv, ah1[3]*inv };
    ((float4*)c0L)[m * (SP / 4) + l] = o0;
    ((float4*)h0L)[m * (SP / 4) + l] = o1;
    ((float4*)c1L)[m * (SP / 4) + l] = o2;
    ((float4*)h1L)[m * (SP / 4) + l] = o3;
    if (l == 0) ipL[m] = wsum;
  } else {
    // step 0: zero states, initial ip = [node==0]
    for (int i2 = tid; i2 < 16 * HH; i2 += 512) {
      int m = i2 >> 7, k = i2 & 127;
      c0L[m * SP + k] = 0.f; h0L[m * SP + k] = 0.f;
      c1L[m * SP + k] = 0.f; h1L[m * SP + k] = 0.f;
    }
    if (tid < 16) ipL[tid] = (((row0 + tid) & (NN - 1)) == 0) ? 1.0f : 0.0f;
  }

  if (!lstmLive) {
    // ----- batch death: exit-owner block computes final logits in-place
    __syncthreads();
    if (tid < 128) {
      exitP[tid] = c0L[exm * SP + tid];
      exitP[128 + tid] = h0L[exm * SP + tid];
      exitP[256 + tid] = c1L[exm * SP + tid];
      exitP[384 + tid] = h1L[exm * SP + tid];
    }
    __syncthreads();
#pragma unroll
    for (int half = 0; half < 2; ++half) {
      int v = half * 512 + tid;
      if (v < OUTV) {
        float acc = bo[v];
#pragma unroll 8
        for (int k = 0; k < 512; ++k) acc += exitP[k] * Wo[(size_t)k * OUTV + v];
        out[b * OUTV + v] = acc;
      }
    }
    return;
  }
  __syncthreads();  // prologue state visible

  // pristine exit-row copy
  if (ownExit && tid < 128) {
    exitP[tid] = c0L[exm * SP + tid];
    exitP[128 + tid] = h0L[exm * SP + tid];
    exitP[256 + tid] = c1L[exm * SP + tid];
    exitP[384 + tid] = h1L[exm * SP + tid];
  }

  // c-state into registers; build bf16 h A-fragments into buffer 0
  float c0r[4], c1r[4], h0r[4], h1r[4];
#pragma unroll
  for (int r = 0; r < 4; ++r) {
    int m = qq * 4 + r;
    c0r[r] = c0L[m * SP + kcol];
    c1r[r] = c1L[m * SP + kcol];
    h0r[r] = h0L[m * SP + kcol];
    h1r[r] = h1L[m * SP + kcol];
    hA0[0][basePos + m * 8] = f2bu(h0r[r]);
    hA1[0][basePos + m * 8] = f2bu(h1r[r]);
  }
  // token-0 tab D-init prefetch (before the fragment barrier)
  f32x4 d0c[4];
#pragma unroll
  for (int g = 0; g < 4; ++g) {
    int colz = (w + 8 * g) * 16 + n16;
#pragma unroll
    for (int r = 0; r < 4; ++r)
      d0c[g][r] = tab[(size_t)toks[(qq * 4 + r) * 4 + 0] * CC + colz];
  }
  __syncthreads();  // fragments ready

  int cur = 0;
  for (int t = 0; t < TT; ++t) {
    const int nxt = cur ^ 1;
    const s16x8* hA0c = (const s16x8*)hA0[cur];
    const s16x8* hA1c = (const s16x8*)hA1[cur];
    s16x8 a0[4], a1b[4];
#pragma unroll
    for (int kb = 0; kb < 4; ++kb) { a0[kb] = hA0c[kb * 64 + lane]; a1b[kb] = hA1c[kb * 64 + lane]; }

    // layer 0 MFMA: z = tab(+b0, prefetched) + h0 @ Wh0
#pragma unroll
    for (int g = 0; g < 4; ++g)
#pragma unroll
      for (int kb = 0; kb < 4; ++kb)
        d0c[g] = __builtin_amdgcn_mfma_f32_16x16x32_bf16(a0[kb], B0f[g][kb], d0c[g], 0, 0, 0);

    // gates 0 in registers; new h0 frags -> OTHER buffer
#pragma unroll
    for (int r = 0; r < 4; ++r) {
      float cn = sigf(d0c[1][r]) * c0r[r] + sigf(d0c[0][r]) * tanhr(d0c[2][r]);
      float hn = sigf(d0c[3][r]) * tanhr(cn);
      c0r[r] = cn; h0r[r] = hn;
      hA0[nxt][basePos + (qq * 4 + r) * 8] = f2bu(hn);
    }
    __syncthreads();  // h0_new fragments visible

    // prefetch next token's tab D-init (overlaps layer-1 MFMA)
    f32x4 d0n[4];
    if (t < TT - 1) {
#pragma unroll
      for (int g = 0; g < 4; ++g) {
        int colz = (w + 8 * g) * 16 + n16;
#pragma unroll
        for (int r = 0; r < 4; ++r)
          d0n[g][r] = tab[(size_t)toks[(qq * 4 + r) * 4 + t + 1] * CC + colz];
      }
    }

    // layer 1 MFMA: z = b1 + h0new @ Wi1 + h1old @ Wh1
    const s16x8* hA0n = (const s16x8*)hA0[nxt];
    s16x8 a1a[4];
#pragma unroll
    for (int kb = 0; kb < 4; ++kb) a1a[kb] = hA0n[kb * 64 + lane];
    f32x4 d1[4];
#pragma unroll
    for (int g = 0; g < 4; ++g) {
      int ci = w + 8 * g;
      s16x8 wi[4];
#pragma unroll
      for (int kb = 0; kb < 4; ++kb) wi[kb] = pWi1[(ci * 4 + kb) * 64 + lane];
      f32x4 d = { b1v[g], b1v[g], b1v[g], b1v[g] };
#pragma unroll
      for (int kb = 0; kb < 4; ++kb)
        d = __builtin_amdgcn_mfma_f32_16x16x32_bf16(a1a[kb], wi[kb], d, 0, 0, 0);
#pragma unroll
      for (int kb = 0; kb < 4; ++kb)
        d = __builtin_amdgcn_mfma_f32_16x16x32_bf16(a1b[kb], B1f[g][kb], d, 0, 0, 0);
      d1[g] = d;
    }

    // gates 1 in registers; new h1 frags -> OTHER buffer
#pragma unroll
    for (int r = 0; r < 4; ++r) {
      float cn = sigf(d1[1][r]) * c1r[r] + sigf(d1[0][r]) * tanhr(d1[2][r]);
      float hn = sigf(d1[3][r]) * tanhr(cn);
      c1r[r] = cn; h1r[r] = hn;
      hA1[nxt][basePos + (qq * 4 + r) * 8] = f2bu(hn);
    }
    __syncthreads();  // h1_new fragments visible for next token
#pragma unroll
    for (int g = 0; g < 4; ++g) d0c[g] = d0n[g];
    cur = nxt;
  }

  // epilogue: regs -> LDS
#pragma unroll
  for (int r = 0; r < 4; ++r) {
    int m = qq * 4 + r;
    c0L[m * SP + kcol] = c0r[r];
    h0L[m * SP + kcol] = h0r[r];
    c1L[m * SP + kcol] = c1r[r];
    h1L[m * SP + kcol] = h1r[r];
  }
  __syncthreads();

  // branch softmax (32 threads/row); exit row uses pristine copy
  {
    const int m = tid >> 5, sub = tid & 31;
    const int row = row0 + m;
    const bool isExit = (m == exm);
    float z0 = 0.f, z1 = 0.f;
#pragma unroll
    for (int u = 0; u < 16; ++u) {
      int k = u * 32 + sub;
      int seg = k >> 7, kk = k & 127;
      float fk;
      if (isExit) {
        fk = exitP[seg * 128 + kk];
      } else {
        fk = (seg == 0) ? c0L[m * SP + kk] : (seg == 1) ? h0L[m * SP + kk]
           : (seg == 2) ? c1L[m * SP + kk] : h1L[m * SP + kk];
      }
      z0 += fk * Wb[2 * k];
      z1 += fk * Wb[2 * k + 1];
    }
#pragma unroll
    for (int off = 16; off >= 1; off >>= 1) {
      z0 += __shfl_xor(z0, off);
      z1 += __shfl_xor(z1, off);
    }
    if (sub == 0) {
      z0 += bb[0]; z1 += bb[1];
      float mx = fmaxf(z0, z1);
      float e0 = __expf(z0 - mx), e1 = __expf(z1 - mx);
      float inv = 1.0f / (e0 + e1);
      float ipv = ipL[m];
      wtW[row] = e0 * inv * ipv;
      wfW[row] = e1 * inv * ipv;
    }
  }

  // writeout: pack to bf16, 2 x dwordx4 per lane; exit row from pristine copy
  {
    const int m = tid >> 5, l = tid & 31;
    const bool ex = (m == exm);
    const int grow = row0 + m;
    float f0[4], f1[4], f2[4], f3[4];
#pragma unroll
    for (int i = 0; i < 4; ++i) {
      int k = 4 * l + i;
      f0[i] = ex ? exitP[k] : c0L[m * SP + k];
      f1[i] = ex ? exitP[128 + k] : h0L[m * SP + k];
      f2[i] = ex ? exitP[256 + k] : c1L[m * SP + k];
      f3[i] = ex ? exitP[384 + k] : h1L[m * SP + k];
    }
    uint4 o0 = { packh(f0[0], f0[1]), packh(f0[2], f0[3]),
                 packh(f1[0], f1[1]), packh(f1[2], f1[3]) };
    uint4 o1 = { packh(f2[0], f2[1]), packh(f2[2], f2[3]),
                 packh(f3[0], f3[1]), packh(f3[2], f3[3]) };
    uint4* pw = (uint4*)(Pw + (size_t)grow * 256 + 8 * l);
    pw[0] = o0; pw[1] = o1;
  }
}

// distinct failure signature if workspace too small: out := 0 -> err == ref absmax
__global__ void zero_out_kernel(float* __restrict__ out, int n) {
  int i = blockIdx.x * blockDim.x + threadIdx.x;
  if (i < n) out[i] = 0.0f;
}

// ---------------- host orchestration ----------------

extern "C" void kernel_launch(void* const* d_in, const int* in_sizes, int n_in,
                              void* d_out, int out_size, void* d_ws, size_t ws_size,
                              hipStream_t stream) {
  const int* data = (const int*)d_in[0];
  const int* tb   = (const int*)d_in[1];
  const int* fb   = (const int*)d_in[2];
  const int* exi  = (const int*)d_in[3];
  const int* steps = (const int*)d_in[4];
  const float* embed = (const float*)d_in[5];
  const float* Wi = (const float*)d_in[6];   // (L,H,4H)
  const float* Wh = (const float*)d_in[7];   // (L,H,4H)
  const float* bl = (const float*)d_in[8];   // (L,4H)
  const float* Wb = (const float*)d_in[9];   // (2LH,2)
  const float* bb = (const float*)d_in[10];  // (2,)
  const float* Wo = (const float*)d_in[11];  // (2LH,OUT)
  const float* bo = (const float*)d_in[12];  // (OUT,)
  float* out = (float*)d_out;

  const float* Wi0 = Wi;
  const float* Wi1 = Wi + HH * CC;
  const float* Wh0 = Wh;
  const float* Wh1 = Wh + HH * CC;
  const float* b0 = bl;
  const float* b1 = bl + CC;

  float* ws = (float*)d_ws;
  size_t off = 0;
  float* tab = ws + off;  off += (size_t)1024 * CC;        // 2 MB
  unsigned int* PA = (unsigned int*)(ws + off); off += (size_t)MM * 256;  // packed state A
  unsigned int* PB = (unsigned int*)(ws + off); off += (size_t)MM * 256;  // packed state B
  unsigned short* swz = (unsigned short*)(ws + off); off += 3 * 32768;    // 3x65536 bf16
  float* wtA = ws + off;  off += MM;
  float* wfA = ws + off;  off += MM;
  float* wtB = ws + off;  off += MM;
  float* wfB = ws + off;  off += MM;
  int* offs  = (int*)(ws + off); off += MM + 16;
  int* edges = (int*)(ws + off); off += 2 * MM;
  (void)in_sizes; (void)n_in; (void)out_size;

  if (ws_size < off * sizeof(float)) {
    zero_out_kernel<<<(BB * OUTV + 255) / 256, 256, 0, stream>>>(out, BB * OUTV);
    return;
  }

  unsigned short* swzWh0 = swz;
  unsigned short* swzWi1 = swz + 65536;
  unsigned short* swzWh1 = swz + 2 * 65536;

  setup_kernel<<<525, 512, 0, stream>>>(tb, fb, offs, edges, Wh0, Wi1, Wh1,
                                        embed, Wi0, b0, swz, tab);

  // dispatch s: prologue aggregates step s-1 (reads other parity), LSTM writes parity s&1.
  // Death step (s == steps[b]) computes that batch's final logits in-place.
  for (int s = 0; s <= MAXS; ++s) {
    unsigned int* Pwp = (s & 1) ? PB : PA;
    const unsigned int* Prp = (s & 1) ? PA : PB;
    float* wtWp = (s & 1) ? wtB : wtA;
    float* wfWp = (s & 1) ? wfB : wfA;
    const float* wtRp = (s & 1) ? wtA : wtB;
    const float* wfRp = (s & 1) ? wfA : wfB;
    step_kernel<<<MM / 16, 512, 0, stream>>>(
        Prp, Pwp, wtRp, wfRp, wtWp, wfWp,
        offs, edges, tab, swzWh0, swzWi1, swzWh1, b1, Wb, bb,
        Wo, bo, out, data, exi, steps, s);
  }
}

// Round 14
// 551.986 us; speedup vs baseline: 1.5199x; 1.5199x over previous
//
#include <hip/hip_runtime.h>
#include <hip/hip_bf16.h>
#include <stdint.h>
#include <stddef.h>

static constexpr int BB = 16, NN = 256, TT = 4, HH = 128;
static constexpr int MM = BB * NN;     // 4096 rows
static constexpr int CC = 512;         // 4*H gate width
static constexpr int OUTV = 1000;
static constexpr int MAXS = 15;
static constexpr int SP = 132;         // f32 state row pitch in LDS

typedef float f32x4 __attribute__((ext_vector_type(4)));
typedef short s16x8 __attribute__((ext_vector_type(8)));

__device__ __forceinline__ float sigf(float x) { return 1.0f / (1.0f + __expf(-x)); }
__device__ __forceinline__ float tanhr(float x) { return 2.0f / (1.0f + __expf(-2.0f * x)) - 1.0f; }
__device__ __forceinline__ unsigned short f2bu(float a) {
  return __builtin_bit_cast(unsigned short, __float2bfloat16(a));
}
__device__ __forceinline__ unsigned int packh(float a, float b) {
  return (unsigned int)f2bu(a) | ((unsigned int)f2bu(b) << 16);
}
__device__ __forceinline__ float blo(unsigned int u) { return __builtin_bit_cast(float, u << 16); }
__device__ __forceinline__ float bhi(unsigned int u) { return __builtin_bit_cast(float, u & 0xffff0000u); }

// ---------------- setup kernels (2 dispatches) ----------------

// per-batch CSR built entirely block-locally in LDS: 16 blocks x 512 threads
__global__ __launch_bounds__(512) void csr_kernel(const int* __restrict__ tb,
                                                  const int* __restrict__ fb,
                                                  int* __restrict__ offs,
                                                  int* __restrict__ edges) {
  const int blk = blockIdx.x;   // batch
  const int tid = threadIdx.x;  // 0..511 (one edge per thread)
  __shared__ int cnt[256], sc[256], cur[256];
  if (tid < 256) cnt[tid] = 0;
  __syncthreads();
  const int n = tid >> 1, bit = tid & 1;
  const int tgt = bit ? fb[blk * NN + n] : tb[blk * NN + n];
  atomicAdd(&cnt[tgt], 1);
  __syncthreads();
  if (tid < 256) sc[tid] = cnt[tid];
  __syncthreads();
  for (int ofs = 1; ofs < 256; ofs <<= 1) {
    int t2 = (tid < 256 && tid >= ofs) ? sc[tid - ofs] : 0;
    __syncthreads();
    if (tid < 256) sc[tid] += t2;
    __syncthreads();
  }
  if (tid < 256) { offs[blk * NN + tid] = blk * 2 * NN + sc[tid] - cnt[tid]; cur[tid] = 0; }
  if (blk == 0 && tid == 0) offs[MM] = 2 * MM;
  __syncthreads();
  int lpos = sc[tgt] - cnt[tgt] + atomicAdd(&cur[tgt], 1);
  edges[blk * 2 * NN + lpos] = (n << 1) | bit;
}

// blocks 0..767: weight swizzle -> bf16 B-fragment order; blocks 768..892: XW0 vocab table
__global__ __launch_bounds__(256) void prep_kernel(
    const float* __restrict__ Wh0, const float* __restrict__ Wi1, const float* __restrict__ Wh1,
    const float* __restrict__ embed, const float* __restrict__ Wi0, const float* __restrict__ b0,
    unsigned short* __restrict__ swz, float* __restrict__ tab) {
  const int blk = blockIdx.x;
  const int tid = threadIdx.x;
  if (blk < 768) {
    int i = blk * 256 + tid;  // 0..196607
    int mtx = i >> 16, ii = i & 65535;
    const float* W = (mtx == 0) ? Wh0 : (mtx == 1) ? Wi1 : Wh1;
    int j = ii & 7, ln = (ii >> 3) & 63, kb = (ii >> 9) & 3, ct = ii >> 11;
    int n = ln & 15, q = ln >> 4;
    swz[i] = f2bu(W[(kb * 32 + q * 8 + j) * CC + ct * 16 + n]);
    return;
  }
  // XW0: tab[v] = embed[v]@Wi0 + b0; 125 blocks x 8 rows = 1000 rows
  const int v0 = (blk - 768) * 8;
  __shared__ float A[8][HH];
  for (int s = tid; s < 8 * HH; s += 256) {
    int r = s >> 7, k = s & 127;
    A[r][k] = embed[(size_t)(v0 + r) * HH + k];
  }
  __syncthreads();
  const int j = tid;
  float za[8], zb[8];
  {
    float ba = b0[j], bbv = b0[j + 256];
#pragma unroll
    for (int r = 0; r < 8; ++r) { za[r] = ba; zb[r] = bbv; }
  }
#pragma unroll 4
  for (int k = 0; k < HH; ++k) {
    float wa = Wi0[k * CC + j], wb = Wi0[k * CC + j + 256];
#pragma unroll
    for (int r = 0; r < 8; ++r) { za[r] += A[r][k] * wa; zb[r] += A[r][k] * wb; }
  }
#pragma unroll
  for (int r = 0; r < 8; ++r) {
    tab[(size_t)(v0 + r) * CC + j] = za[r];
    tab[(size_t)(v0 + r) * CC + j + 256] = zb[r];
  }
}

// ---------------- fused per-step kernel ----------------
// 16 rows/block, 512 threads = 8 waves; XCD-pinned batches (blockIdx === b mod 8).
// Hoisted persistent B-fragment loads; double-buffered hA; bf16-packed state.
// Death step (s == steps[b]): only the exit-owner block aggregates and writes a
// 512-float fin record; all other blocks of the dead batch return immediately.

__global__ __launch_bounds__(512) void step_kernel(
    const unsigned int* __restrict__ Pr, unsigned int* __restrict__ Pw,
    const float* __restrict__ wtR, const float* __restrict__ wfR,
    float* __restrict__ wtW, float* __restrict__ wfW,
    float* __restrict__ fin,
    const int* __restrict__ offs, const int* __restrict__ edges,
    const float* __restrict__ tab,
    const unsigned short* __restrict__ swzWh0, const unsigned short* __restrict__ swzWi1,
    const unsigned short* __restrict__ swzWh1, const float* __restrict__ b1,
    const float* __restrict__ Wb, const float* __restrict__ bb,
    const int* __restrict__ data, const int* __restrict__ exi,
    const int* __restrict__ steps, int step) {
  const int B = blockIdx.x;
  const int b = (B & 7) | (((B >> 3) & 1) << 3);  // batch, pinned to XCD b%8
  const int g16 = B >> 4;                          // node-group 0..15 within batch
  const int row0 = b * NN + g16 * 16;
  const int sb = steps[b];
  const bool aggLive = (step >= 1) && ((step - 1) < sb);
  const bool lstmLive = (step < sb);
  if (!aggLive && !lstmLive) return;

  const int exnode = exi[b];
  const int exm = exnode - (g16 * 16);
  const bool ownExit = (exm >= 0 && exm < 16);
  if (!lstmLive && !ownExit) return;  // dead batch, non-exit block: nothing to do

  const int tid = threadIdx.x;
  const int w = tid >> 6;
  const int lane = tid & 63;
  const int n16 = lane & 15, qq = lane >> 4;
  const int kcol = w * 16 + n16;
  const int basePos = ((kcol >> 5) * 64 + ((kcol >> 3) & 3) * 16) * 8 + (kcol & 7);

  __shared__ float c0L[16 * SP], h0L[16 * SP], c1L[16 * SP], h1L[16 * SP];
  __shared__ __align__(16) unsigned short hA0[2][2048], hA1[2][2048];  // double-buffered
  __shared__ float exitP[512];
  __shared__ float ipL[16];
  __shared__ int toks[64];

  // ----- HOISTED persistent loads: in flight during the gather
  s16x8 B0f[4][4], B1f[4][4];
  float b1v[4];
  const s16x8* pWh0 = (const s16x8*)swzWh0;
  const s16x8* pWh1 = (const s16x8*)swzWh1;
  const s16x8* pWi1 = (const s16x8*)swzWi1;
  if (lstmLive) {
#pragma unroll
    for (int g = 0; g < 4; ++g) {
      int ci = w + 8 * g;
#pragma unroll
      for (int kb = 0; kb < 4; ++kb) {
        B0f[g][kb] = pWh0[(ci * 4 + kb) * 64 + lane];
        B1f[g][kb] = pWh1[(ci * 4 + kb) * 64 + lane];
      }
      b1v[g] = b1[ci * 16 + n16];
    }
    if (tid < 64) toks[tid] = data[(row0 + (tid >> 2)) * TT + (tid & 3)];
  }

  // ----- prologue: aggregate previous step (16 nodes, 32 lanes each)
  if (aggLive) {
    const int l = tid & 31;
    const int m = tid >> 5;
    const int node = row0 + m;
    const int beg = offs[node], end = offs[node + 1];
    float ac0[4] = {0,0,0,0}, ah0[4] = {0,0,0,0}, ac1[4] = {0,0,0,0}, ah1[4] = {0,0,0,0};
    float wsum = 0.f;
    for (int e = beg; e < end; ++e) {
      int rec = edges[e];
      int src = (b << 8) + (rec >> 1);
      float wv = (rec & 1) ? wfR[src] : wtR[src];
      wsum += wv;
      const uint4* pr = (const uint4*)(Pr + (size_t)src * 256 + 8 * l);
      uint4 u0 = pr[0], u1 = pr[1];
      ac0[0] += wv * blo(u0.x); ac0[1] += wv * bhi(u0.x);
      ac0[2] += wv * blo(u0.y); ac0[3] += wv * bhi(u0.y);
      ah0[0] += wv * blo(u0.z); ah0[1] += wv * bhi(u0.z);
      ah0[2] += wv * blo(u0.w); ah0[3] += wv * bhi(u0.w);
      ac1[0] += wv * blo(u1.x); ac1[1] += wv * bhi(u1.x);
      ac1[2] += wv * blo(u1.y); ac1[3] += wv * bhi(u1.y);
      ah1[0] += wv * blo(u1.z); ah1[1] += wv * bhi(u1.z);
      ah1[2] += wv * blo(u1.w); ah1[3] += wv * bhi(u1.w);
    }
    float inv = 1.0f / (wsum + 1e-7f);
    float4 o0 = { ac0[0]*inv, ac0[1]*inv, ac0[2]*inv, ac0[3]*inv };
    float4 o1 = { ah0[0]*inv, ah0[1]*inv, ah0[2]*inv, ah0[3]*inv };
    float4 o2 = { ac1[0]*inv, ac1[1]*inv, ac1[2]*inv, ac1[3]*inv };
    float4 o3 = { ah1[0]*inv, ah1[1]*inv, ah1[2]*inv, ah1[3]*inv };
    if (!lstmLive) {
      // batch death: persist ONLY the exit node's aggregated feats (512 floats)
      if (m == exm) {
        ((float4*)(fin + b * 512))[l] = o0;
        ((float4*)(fin + b * 512 + 128))[l] = o1;
        ((float4*)(fin + b * 512 + 256))[l] = o2;
        ((float4*)(fin + b * 512 + 384))[l] = o3;
      }
      return;  // block-uniform (lstmLive uniform per block)
    }
    ((float4*)c0L)[m * (SP / 4) + l] = o0;
    ((float4*)h0L)[m * (SP / 4) + l] = o1;
    ((float4*)c1L)[m * (SP / 4) + l] = o2;
    ((float4*)h1L)[m * (SP / 4) + l] = o3;
    if (l == 0) ipL[m] = wsum;
  } else {
    // step 0: zero states, initial ip = [node==0]
    for (int i2 = tid; i2 < 16 * HH; i2 += 512) {
      int m = i2 >> 7, k = i2 & 127;
      c0L[m * SP + k] = 0.f; h0L[m * SP + k] = 0.f;
      c1L[m * SP + k] = 0.f; h1L[m * SP + k] = 0.f;
    }
    if (tid < 16) ipL[tid] = (((row0 + tid) & (NN - 1)) == 0) ? 1.0f : 0.0f;
  }

  __syncthreads();  // prologue state visible

  // pristine exit-row copy
  if (ownExit && tid < 128) {
    exitP[tid] = c0L[exm * SP + tid];
    exitP[128 + tid] = h0L[exm * SP + tid];
    exitP[256 + tid] = c1L[exm * SP + tid];
    exitP[384 + tid] = h1L[exm * SP + tid];
  }

  // c-state into registers; build bf16 h A-fragments into buffer 0
  float c0r[4], c1r[4], h0r[4], h1r[4];
#pragma unroll
  for (int r = 0; r < 4; ++r) {
    int m = qq * 4 + r;
    c0r[r] = c0L[m * SP + kcol];
    c1r[r] = c1L[m * SP + kcol];
    h0r[r] = h0L[m * SP + kcol];
    h1r[r] = h1L[m * SP + kcol];
    hA0[0][basePos + m * 8] = f2bu(h0r[r]);
    hA1[0][basePos + m * 8] = f2bu(h1r[r]);
  }
  __syncthreads();  // fragments ready

  int cur = 0;
  for (int t = 0; t < TT; ++t) {
    const int nxt = cur ^ 1;
    const s16x8* hA0c = (const s16x8*)hA0[cur];
    const s16x8* hA1c = (const s16x8*)hA1[cur];
    s16x8 a0[4], a1b[4];
#pragma unroll
    for (int kb = 0; kb < 4; ++kb) { a0[kb] = hA0c[kb * 64 + lane]; a1b[kb] = hA1c[kb * 64 + lane]; }
    f32x4 d0[4];
#pragma unroll
    for (int g = 0; g < 4; ++g) {
      int colz = (w + 8 * g) * 16 + n16;
#pragma unroll
      for (int r = 0; r < 4; ++r)
        d0[g][r] = tab[(size_t)toks[(qq * 4 + r) * 4 + t] * CC + colz];
    }

    // layer 0 MFMA: z = tab(+b0) + h0 @ Wh0
#pragma unroll
    for (int g = 0; g < 4; ++g)
#pragma unroll
      for (int kb = 0; kb < 4; ++kb)
        d0[g] = __builtin_amdgcn_mfma_f32_16x16x32_bf16(a0[kb], B0f[g][kb], d0[g], 0, 0, 0);

    // gates 0 in registers; new h0 frags -> OTHER buffer (no WAR hazard barrier)
#pragma unroll
    for (int r = 0; r < 4; ++r) {
      float cn = sigf(d0[1][r]) * c0r[r] + sigf(d0[0][r]) * tanhr(d0[2][r]);
      float hn = sigf(d0[3][r]) * tanhr(cn);
      c0r[r] = cn; h0r[r] = hn;
      hA0[nxt][basePos + (qq * 4 + r) * 8] = f2bu(hn);
    }
    __syncthreads();  // h0_new fragments visible

    // layer 1 MFMA: z = b1 + h0new @ Wi1 + h1old @ Wh1
    const s16x8* hA0n = (const s16x8*)hA0[nxt];
    s16x8 a1a[4];
#pragma unroll
    for (int kb = 0; kb < 4; ++kb) a1a[kb] = hA0n[kb * 64 + lane];
    f32x4 d1[4];
#pragma unroll
    for (int g = 0; g < 4; ++g) {
      int ci = w + 8 * g;
      s16x8 wi[4];
#pragma unroll
      for (int kb = 0; kb < 4; ++kb) wi[kb] = pWi1[(ci * 4 + kb) * 64 + lane];
      f32x4 d = { b1v[g], b1v[g], b1v[g], b1v[g] };
#pragma unroll
      for (int kb = 0; kb < 4; ++kb)
        d = __builtin_amdgcn_mfma_f32_16x16x32_bf16(a1a[kb], wi[kb], d, 0, 0, 0);
#pragma unroll
      for (int kb = 0; kb < 4; ++kb)
        d = __builtin_amdgcn_mfma_f32_16x16x32_bf16(a1b[kb], B1f[g][kb], d, 0, 0, 0);
      d1[g] = d;
    }

    // gates 1 in registers; new h1 frags -> OTHER buffer
#pragma unroll
    for (int r = 0; r < 4; ++r) {
      float cn = sigf(d1[1][r]) * c1r[r] + sigf(d1[0][r]) * tanhr(d1[2][r]);
      float hn = sigf(d1[3][r]) * tanhr(cn);
      c1r[r] = cn; h1r[r] = hn;
      hA1[nxt][basePos + (qq * 4 + r) * 8] = f2bu(hn);
    }
    __syncthreads();  // h1_new fragments visible for next token
    cur = nxt;
  }

  // epilogue: regs -> LDS
#pragma unroll
  for (int r = 0; r < 4; ++r) {
    int m = qq * 4 + r;
    c0L[m * SP + kcol] = c0r[r];
    h0L[m * SP + kcol] = h0r[r];
    c1L[m * SP + kcol] = c1r[r];
    h1L[m * SP + kcol] = h1r[r];
  }
  __syncthreads();

  // branch softmax (32 threads/row); exit row uses pristine copy
  {
    const int m = tid >> 5, sub = tid & 31;
    const int row = row0 + m;
    const bool isExit = (m == exm);
    float z0 = 0.f, z1 = 0.f;
#pragma unroll
    for (int u = 0; u < 16; ++u) {
      int k = u * 32 + sub;
      int seg = k >> 7, kk = k & 127;
      float fk;
      if (isExit) {
        fk = exitP[seg * 128 + kk];
      } else {
        fk = (seg == 0) ? c0L[m * SP + kk] : (seg == 1) ? h0L[m * SP + kk]
           : (seg == 2) ? c1L[m * SP + kk] : h1L[m * SP + kk];
      }
      z0 += fk * Wb[2 * k];
      z1 += fk * Wb[2 * k + 1];
    }
#pragma unroll
    for (int off = 16; off >= 1; off >>= 1) {
      z0 += __shfl_xor(z0, off);
      z1 += __shfl_xor(z1, off);
    }
    if (sub == 0) {
      z0 += bb[0]; z1 += bb[1];
      float mx = fmaxf(z0, z1);
      float e0 = __expf(z0 - mx), e1 = __expf(z1 - mx);
      float inv = 1.0f / (e0 + e1);
      float ipv = ipL[m];
      wtW[row] = e0 * inv * ipv;
      wfW[row] = e1 * inv * ipv;
    }
  }

  // writeout: pack to bf16, 2 x dwordx4 per lane; exit row from pristine copy
  {
    const int m = tid >> 5, l = tid & 31;
    const bool ex = (m == exm);
    const int grow = row0 + m;
    float f0[4], f1[4], f2[4], f3[4];
#pragma unroll
    for (int i = 0; i < 4; ++i) {
      int k = 4 * l + i;
      f0[i] = ex ? exitP[k] : c0L[m * SP + k];
      f1[i] = ex ? exitP[128 + k] : h0L[m * SP + k];
      f2[i] = ex ? exitP[256 + k] : c1L[m * SP + k];
      f3[i] = ex ? exitP[384 + k] : h1L[m * SP + k];
    }
    uint4 o0 = { packh(f0[0], f0[1]), packh(f0[2], f0[3]),
                 packh(f1[0], f1[1]), packh(f1[2], f1[3]) };
    uint4 o1 = { packh(f2[0], f2[1]), packh(f2[2], f2[3]),
                 packh(f3[0], f3[1]), packh(f3[2], f3[3]) };
    uint4* pw = (uint4*)(Pw + (size_t)grow * 256 + 8 * l);
    pw[0] = o0; pw[1] = o1;
  }
}

// logits: 64 blocks (16 batches x 4 col-tiles of 250), 256 threads; reads fin records
__global__ void final_kernel(const float* __restrict__ fin, const float* __restrict__ Wo,
                             const float* __restrict__ bo, float* __restrict__ out) {
  const int b = blockIdx.x >> 2;
  const int vt = blockIdx.x & 3;
  const int tid = threadIdx.x;  // 256
  __shared__ float f[512];
  f[tid] = fin[b * 512 + tid];
  f[256 + tid] = fin[b * 512 + 256 + tid];
  __syncthreads();
  if (tid < 250) {
    int v = vt * 250 + tid;
    float acc = bo[v];
#pragma unroll 8
    for (int k = 0; k < 512; ++k) acc += f[k] * Wo[(size_t)k * OUTV + v];
    out[b * OUTV + v] = acc;
  }
}

// distinct failure signature if workspace too small: out := 0 -> err == ref absmax
__global__ void zero_out_kernel(float* __restrict__ out, int n) {
  int i = blockIdx.x * blockDim.x + threadIdx.x;
  if (i < n) out[i] = 0.0f;
}

// ---------------- host orchestration ----------------

extern "C" void kernel_launch(void* const* d_in, const int* in_sizes, int n_in,
                              void* d_out, int out_size, void* d_ws, size_t ws_size,
                              hipStream_t stream) {
  const int* data = (const int*)d_in[0];
  const int* tb   = (const int*)d_in[1];
  const int* fb   = (const int*)d_in[2];
  const int* exi  = (const int*)d_in[3];
  const int* steps = (const int*)d_in[4];
  const float* embed = (const float*)d_in[5];
  const float* Wi = (const float*)d_in[6];   // (L,H,4H)
  const float* Wh = (const float*)d_in[7];   // (L,H,4H)
  const float* bl = (const float*)d_in[8];   // (L,4H)
  const float* Wb = (const float*)d_in[9];   // (2LH,2)
  const float* bb = (const float*)d_in[10];  // (2,)
  const float* Wo = (const float*)d_in[11];  // (2LH,OUT)
  const float* bo = (const float*)d_in[12];  // (OUT,)
  float* out = (float*)d_out;

  const float* Wi0 = Wi;
  const float* Wi1 = Wi + HH * CC;
  const float* Wh0 = Wh;
  const float* Wh1 = Wh + HH * CC;
  const float* b0 = bl;
  const float* b1 = bl + CC;

  float* ws = (float*)d_ws;
  size_t off = 0;
  float* tab = ws + off;  off += (size_t)1024 * CC;        // 2 MB
  unsigned int* PA = (unsigned int*)(ws + off); off += (size_t)MM * 256;  // packed state A
  unsigned int* PB = (unsigned int*)(ws + off); off += (size_t)MM * 256;  // packed state B
  unsigned short* swz = (unsigned short*)(ws + off); off += 3 * 32768;    // 3x65536 bf16
  float* wtA = ws + off;  off += MM;
  float* wfA = ws + off;  off += MM;
  float* wtB = ws + off;  off += MM;
  float* wfB = ws + off;  off += MM;
  float* fin = ws + off;  off += BB * 512;                 // death exit records
  int* offs  = (int*)(ws + off); off += MM + 16;
  int* edges = (int*)(ws + off); off += 2 * MM;
  (void)in_sizes; (void)n_in; (void)out_size;

  if (ws_size < off * sizeof(float)) {
    zero_out_kernel<<<(BB * OUTV + 255) / 256, 256, 0, stream>>>(out, BB * OUTV);
    return;
  }

  unsigned short* swzWh0 = swz;
  unsigned short* swzWi1 = swz + 65536;
  unsigned short* swzWh1 = swz + 2 * 65536;

  csr_kernel<<<BB, 512, 0, stream>>>(tb, fb, offs, edges);
  prep_kernel<<<893, 256, 0, stream>>>(Wh0, Wi1, Wh1, embed, Wi0, b0, swz, tab);

  // dispatch s: prologue aggregates step s-1 (reads other parity), LSTM writes parity s&1.
  // Death step (s == steps[b]): exit-owner block writes fin[b] only.
  for (int s = 0; s <= MAXS; ++s) {
    unsigned int* Pwp = (s & 1) ? PB : PA;
    const unsigned int* Prp = (s & 1) ? PA : PB;
    float* wtWp = (s & 1) ? wtB : wtA;
    float* wfWp = (s & 1) ? wfB : wfA;
    const float* wtRp = (s & 1) ? wtA : wtB;
    const float* wfRp = (s & 1) ? wfA : wfB;
    step_kernel<<<MM / 16, 512, 0, stream>>>(
        Prp, Pwp, wtRp, wfRp, wtWp, wfWp, fin,
        offs, edges, tab, swzWh0, swzWi1, swzWh1, b1, Wb, bb,
        data, exi, steps, s);
  }
  final_kernel<<<BB * 4, 256, 0, stream>>>(fin, Wo, bo, out);
}